// Round 3
// baseline (157.349 us; speedup 1.0000x reference)
//
#include <hip/hip_runtime.h>
#include <hip/hip_bf16.h>

typedef __hip_bfloat16 bf16;
typedef unsigned short u16;
typedef unsigned int u32;

typedef __bf16 bf16x8 __attribute__((ext_vector_type(8)));
typedef float f32x4 __attribute__((ext_vector_type(4)));

__device__ __forceinline__ float bf2f(bf16 v) { return __bfloat162float(v); }
__device__ __forceinline__ float us2f(u16 u) {
    union { u32 i; float f; } c; c.i = ((u32)u) << 16; return c.f;
}
__device__ __forceinline__ u16 f2u(float f) {
    union { bf16 b; u16 u; } c; c.b = __float2bfloat16(f); return c.u;
}

// ---------------------------------------------------------------------------
// K1 (MFMA GEMM): km/qm/xm = conv1x1. Blocks 0..63 zero the covariance
// partials arena; block 0 zeroes the completion counter for k_attn's
// last-block stats pass.
// ---------------------------------------------------------------------------
__global__ __launch_bounds__(256) void k_proj(
    const float* __restrict__ x, const float* __restrict__ vessel,
    const float* __restrict__ wk, const float* __restrict__ bk,
    const float* __restrict__ wq, const float* __restrict__ bq,
    const float* __restrict__ wx, const float* __restrict__ bx,
    bf16* __restrict__ km, bf16* __restrict__ qm, bf16* __restrict__ xm,
    float* __restrict__ partials, unsigned int* __restrict__ counter)
{
    __shared__ u16 xs[64 * 264];
    __shared__ u16 wsh[48 * 264];
    const int tid = threadIdx.x;
    const int bid = blockIdx.x;
    const int nh = bid & 1;
    const int pt = bid >> 1;
    const int b  = pt >> 6;
    const int p0 = (pt & 63) * 64;

    if (bid < 64) {
#pragma unroll
        for (int i = 0; i < 5; ++i) {
            const int idx = tid + i * 256;
            if (idx < 1056) partials[bid * 1056 + idx] = 0.f;
        }
        if (bid == 0 && tid == 0) counter[0] = 0u;
    }

#pragma unroll
    for (int i = 0; i < 16; ++i) {
        const int idx4 = tid + i * 256;
        const int ch = idx4 >> 4;
        const int px4 = (idx4 & 15) * 4;
        const float4 v = *(const float4*)&x[(b * 256 + ch) * 4096 + p0 + px4];
        xs[(px4 + 0) * 264 + ch] = f2u(v.x);
        xs[(px4 + 1) * 264 + ch] = f2u(v.y);
        xs[(px4 + 2) * 264 + ch] = f2u(v.z);
        xs[(px4 + 3) * 264 + ch] = f2u(v.w);
    }
#pragma unroll
    for (int i = 0; i < 12; ++i) {
        const int idx4 = tid + i * 256;
        const int o = idx4 >> 6;
        const int ch4 = (idx4 & 63) * 4;
        const int go = nh * 48 + o;
        const float* wp = (go < 32) ? wk : ((go < 64) ? wq : wx);
        const float4 v = *(const float4*)&wp[(go & 31) * 256 + ch4];
        wsh[o * 264 + ch4 + 0] = f2u(v.x);
        wsh[o * 264 + ch4 + 1] = f2u(v.y);
        wsh[o * 264 + ch4 + 2] = f2u(v.z);
        wsh[o * 264 + ch4 + 3] = f2u(v.w);
    }
    __syncthreads();

    const int w = tid >> 6;
    const int lane = tid & 63;
    const int lm = lane & 15, quad = lane >> 4;

    f32x4 acc0 = {0.f, 0.f, 0.f, 0.f};
    f32x4 acc1 = {0.f, 0.f, 0.f, 0.f};
    f32x4 acc2 = {0.f, 0.f, 0.f, 0.f};
#pragma unroll
    for (int kk = 0; kk < 8; ++kk) {
        const int k0 = kk * 32 + quad * 8;
        const bf16x8 a  = *(const bf16x8*)&xs[(w * 16 + lm) * 264 + k0];
        const bf16x8 b0 = *(const bf16x8*)&wsh[(0 + lm) * 264 + k0];
        const bf16x8 b1 = *(const bf16x8*)&wsh[(16 + lm) * 264 + k0];
        const bf16x8 b2 = *(const bf16x8*)&wsh[(32 + lm) * 264 + k0];
        acc0 = __builtin_amdgcn_mfma_f32_16x16x32_bf16(a, b0, acc0, 0, 0, 0);
        acc1 = __builtin_amdgcn_mfma_f32_16x16x32_bf16(a, b1, acc1, 0, 0, 0);
        acc2 = __builtin_amdgcn_mfma_f32_16x16x32_bf16(a, b2, acc2, 0, 0, 0);
    }
#pragma unroll
    for (int t = 0; t < 3; ++t) {
        const f32x4 acc = (t == 0) ? acc0 : ((t == 1) ? acc1 : acc2);
        const int go = nh * 48 + t * 16 + lm;
        const float* bs = (go < 32) ? bk : ((go < 64) ? bq : bx);
        const float bias = bs[go & 31];
        bf16* dst = (go < 32) ? km : ((go < 64) ? qm : xm);
#pragma unroll
        for (int rg = 0; rg < 4; ++rg) {
            const int px = p0 + w * 16 + quad * 4 + rg;
            float vv = acc[rg] + bias;
            if (go < 32) vv *= vessel[b * 4096 + px];
            dst[(b * 4096 + px) * 32 + (go & 31)] = __float2bfloat16(vv);
        }
    }
}

// ---------------------------------------------------------------------------
// K2 (MFMA): 4-scale local attention. Block = 4x4 px tile (16 px),
// grid 1024 -> 4 blocks/CU resident. Halo 12x12=144 pos; Phase A = 9 MFMA
// tiles, Phase B = 9 pos/thread (16 threads/px), Phase C K=160 (padded).
// LDS ~31 KB. Last block (device atomic counter) runs BN stats in-kernel.
// Stats reads of `partials` use agent-scope atomic loads (Guideline 16:
// data was written by other XCDs' atomics; plain loads may be stale).
// ---------------------------------------------------------------------------
__global__ __launch_bounds__(256, 4) void k_attn(
    const bf16* __restrict__ km, const bf16* __restrict__ qm,
    const bf16* __restrict__ xm, bf16* __restrict__ pre,
    float* __restrict__ partials, unsigned int* __restrict__ counter,
    const float* __restrict__ wf, const float* __restrict__ gamma,
    const float* __restrict__ beta,
    float* __restrict__ Aout, float* __restrict__ Sout,
    u16* __restrict__ wfh, u16* __restrict__ wfl)
{
    __shared__ u16 kT[144 * 40];     // 11520 B; aliases P[16*168] & stats cov
    __shared__ u16 xTt[32 * 168];    // 10752 B  [ch][pos], pos 144..167 zero
    __shared__ float S[16 * 148];    //  9472 B  [px][pos]; aliases preT[32*40]
    __shared__ int lastFlag;
    u16* P = kT;                     // P[px*168+pos] (kT dead after Phase A)
    u16* preT = (u16*)S;             // preT[ch*40+px] (S dead after Phase B)

    const int tid = threadIdx.x;
    const int b = blockIdx.x >> 8;
    const int t256 = blockIdx.x & 255;
    const int h0 = (t256 >> 4) * 4;          // 16 row-tiles of 4
    const int w0 = (t256 & 15) * 4;          // 16 col-tiles of 4
    const u16* uk = (const u16*)km;
    const u16* ux = (const u16*)xm;
    const u16* uq = (const u16*)qm;
    const uint4 z4 = {0u, 0u, 0u, 0u};

    // stage kT [pos][ch] + xTt [ch][pos] (transposed): 144 pos x 4 c8
#pragma unroll
    for (int i = 0; i < 3; ++i) {
        const int idx4 = tid + i * 256;      // 0..767, guard 576
        if (idx4 < 576) {
            const int pos = idx4 >> 2, c8 = idx4 & 3;
            const int hy = (pos * 683) >> 13, hx = pos - hy * 12;
            const int gh = h0 - 4 + hy, gw = w0 - 4 + hx;
            uint4 kv = z4, xv = z4;
            if (gh >= 0 && gh < 64 && gw >= 0 && gw < 64) {
                const int g = ((b << 12) + (gh << 6) + gw) * 32 + c8 * 8;
                kv = *(const uint4*)&uk[g];
                xv = *(const uint4*)&ux[g];
            }
            *(uint4*)&kT[pos * 40 + c8 * 8] = kv;
            const u16* xu = (const u16*)&xv;
#pragma unroll
            for (int t = 0; t < 8; ++t)
                xTt[(c8 * 8 + t) * 168 + pos] = xu[t];
        }
    }
    // zero xTt K-pad (pos 144..167 for all 32 ch): u32 words ch*84+72..83
#pragma unroll
    for (int i = 0; i < 2; ++i) {
        const int id = tid + i * 256;
        const int ch = id >> 4, j = id & 15;
        if (j < 12) ((u32*)xTt)[ch * 84 + 72 + j] = 0u;
    }
    __syncthreads();

    const int w = tid >> 6;
    const int lane = tid & 63;
    const int lm = lane & 15, quad = lane >> 4;

    // Phase A: S(16 px x 144 pos), 9 n-tiles over 4 waves. Q from global.
    {
        const int qgh = h0 + (lm >> 2), qgw = w0 + (lm & 3);
        const bf16x8 a =
            *(const bf16x8*)&uq[(((b << 12) + (qgh << 6) + qgw) << 5) + quad * 8];
        for (int n = w; n < 9; n += 4) {
            const bf16x8 bb = *(const bf16x8*)&kT[(n * 16 + lm) * 40 + quad * 8];
            f32x4 acc = {0.f, 0.f, 0.f, 0.f};
            acc = __builtin_amdgcn_mfma_f32_16x16x32_bf16(a, bb, acc, 0, 0, 0);
#pragma unroll
            for (int rg = 0; rg < 4; ++rg)
                S[(quad * 4 + rg) * 148 + n * 16 + lm] = acc[rg];
        }
    }
    __syncthreads();

    // Phase B: 16 threads/px, 9 positions each
    const int px = tid >> 4, cg = tid & 15;
    const int ty = px >> 2, tx = px & 3;
    float e[9];
    float Z3 = 0.f, Z5 = 0.f, Z7 = 0.f, Z9 = 0.f;
#pragma unroll
    for (int i = 0; i < 9; ++i) {
        const int pos = cg + 16 * i;
        const int hy = (pos * 683) >> 13, hx = pos - hy * 12;
        const int dy = hy - 4 - ty, dx = hx - 4 - tx;
        const int ady = dy < 0 ? -dy : dy, adx = dx < 0 ? -dx : dx;
        const int r = ady > adx ? ady : adx;
        const float s = S[px * 148 + pos];
        const float ev = (r <= 4) ? __expf(s) : 0.f;
        e[i] = ev;
        if (r <= 1) Z3 += ev;
        if (r <= 2) Z5 += ev;
        if (r <= 3) Z7 += ev;
        Z9 += ev;
    }
#pragma unroll
    for (int m = 1; m <= 8; m <<= 1) {
        Z3 += __shfl_xor(Z3, m);
        Z5 += __shfl_xor(Z5, m);
        Z7 += __shfl_xor(Z7, m);
        Z9 += __shfl_xor(Z9, m);
    }
    const float iZ3 = 1.f / Z3, iZ5 = 1.f / Z5, iZ7 = 1.f / Z7, iZ9 = 1.f / Z9;
#pragma unroll
    for (int i = 0; i < 9; ++i) {
        const int pos = cg + 16 * i;
        const int hy = (pos * 683) >> 13, hx = pos - hy * 12;
        const int dy = hy - 4 - ty, dx = hx - 4 - tx;
        const int ady = dy < 0 ? -dy : dy, adx = dx < 0 ? -dx : dx;
        const int r = ady > adx ? ady : adx;
        float coef = iZ9;
        if (r <= 1) coef += iZ3;
        if (r <= 2) coef += iZ5;
        if (r <= 3) coef += iZ7;
        P[px * 168 + pos] = f2u(e[i] * coef);
    }
    // zero P K-pad (pos 144..167): u32 words px*84+72..83
    if (cg < 12) ((u32*)P)[px * 84 + 72 + cg] = 0u;
    __syncthreads();

    // Phase C: pre(16x32) = P(16x160) . X^T, waves 0,1 (n-tile = wave id).
    // All threads zero preT's px-pad columns 16..31 first (S arena is dead).
    {
        const int ch = tid >> 3, j = tid & 7;
        ((u32*)preT)[ch * 20 + 8 + j] = 0u;
    }
    if (w < 2) {
        const int n0 = w;
        f32x4 acc = {0.f, 0.f, 0.f, 0.f};
#pragma unroll
        for (int kk = 0; kk < 5; ++kk) {
            const int k0 = kk * 32 + quad * 8;
            const bf16x8 a = *(const bf16x8*)&P[lm * 168 + k0];
            const bf16x8 bb = *(const bf16x8*)&xTt[(n0 * 16 + lm) * 168 + k0];
            acc = __builtin_amdgcn_mfma_f32_16x16x32_bf16(a, bb, acc, 0, 0, 0);
        }
#pragma unroll
        for (int rg = 0; rg < 4; ++rg) {
            const int pl = quad * 4 + rg;
            const int gh = h0 + (pl >> 2), gw = w0 + (pl & 3);
            pre[(((b << 12) + (gh << 6) + gw) << 5) + n0 * 16 + lm] =
                __float2bfloat16(acc[rg]);
            preT[(n0 * 16 + lm) * 40 + pl] = f2u(acc[rg]);
        }
    }
    __syncthreads();

    // Covariance partial via MFMA (K=32 px, upper 16 zero-padded)
    const int it = w >> 1, jt = w & 1;
    const bf16x8 ca = *(const bf16x8*)&preT[(it * 16 + lm) * 40 + quad * 8];
    const bf16x8 cb = *(const bf16x8*)&preT[(jt * 16 + lm) * 40 + quad * 8];
    f32x4 cacc = {0.f, 0.f, 0.f, 0.f};
    cacc = __builtin_amdgcn_mfma_f32_16x16x32_bf16(ca, cb, cacc, 0, 0, 0);
    float* pslot = &partials[(blockIdx.x & 63) * 1056];
#pragma unroll
    for (int rg = 0; rg < 4; ++rg) {
        const int ii = it * 16 + quad * 4 + rg, jj = jt * 16 + lm;
        atomicAdd(&pslot[ii * 32 + jj], cacc[rg]);
    }
    // Per-channel sums: 128 threads, 4 segments of 4 px, shfl-reduce.
    if (tid < 128) {
        const int cc = tid >> 2, sg = tid & 3;
        float s = 0.f;
#pragma unroll
        for (int p = 0; p < 4; ++p) s += us2f(preT[cc * 40 + sg * 4 + p]);
        s += __shfl_xor(s, 1);
        s += __shfl_xor(s, 2);
        if (sg == 0) atomicAdd(&pslot[1024 + cc], s);
    }

    // ---- last-block BN stats (replaces the k_stats launch) ----
    __syncthreads();   // drains all this block's atomics (vmcnt(0) at barrier)
    if (tid == 0) {
        __threadfence();
        const unsigned int old = atomicAdd(counter, 1u);
        lastFlag = (old == 1023u) ? 1 : 0;
    }
    __syncthreads();
    if (lastFlag) {
        float* cov = (float*)kT;           // 4096 B, arena dead
        float* mu  = cov + 1024;           //  128 B
        float4 a4 = {0.f, 0.f, 0.f, 0.f};
        for (int blk = 0; blk < 64; ++blk) {
            const float* pp = &partials[blk * 1056 + tid * 4];
            a4.x += __hip_atomic_load(&pp[0], __ATOMIC_RELAXED, __HIP_MEMORY_SCOPE_AGENT);
            a4.y += __hip_atomic_load(&pp[1], __ATOMIC_RELAXED, __HIP_MEMORY_SCOPE_AGENT);
            a4.z += __hip_atomic_load(&pp[2], __ATOMIC_RELAXED, __HIP_MEMORY_SCOPE_AGENT);
            a4.w += __hip_atomic_load(&pp[3], __ATOMIC_RELAXED, __HIP_MEMORY_SCOPE_AGENT);
        }
        *(float4*)&cov[tid * 4] = a4;
        if (tid < 32) {
            float s = 0.f;
            for (int blk = 0; blk < 64; ++blk)
                s += __hip_atomic_load(&partials[blk * 1056 + 1024 + tid],
                                       __ATOMIC_RELAXED, __HIP_MEMORY_SCOPE_AGENT);
            mu[tid] = s * (1.f / 16384.f);
        }
        __syncthreads();
        float wo[32];
#pragma unroll
        for (int c = 0; c < 32; ++c) wo[c] = wf[tid * 32 + c];

        __attribute__((aligned(16))) u16 hb[32];
        __attribute__((aligned(16))) u16 lb[32];
#pragma unroll
        for (int c = 0; c < 32; ++c) {
            const float v = wo[c];
            const u16 h = f2u(v);
            hb[c] = h;
            lb[c] = f2u(v - us2f(h));
        }
#pragma unroll
        for (int c8 = 0; c8 < 4; ++c8) {
            *(uint4*)&wfh[tid * 32 + c8 * 8] = *(const uint4*)&hb[c8 * 8];
            *(uint4*)&wfl[tid * 32 + c8 * 8] = *(const uint4*)&lb[c8 * 8];
        }

        float mv = 0.f;
#pragma unroll
        for (int c = 0; c < 32; ++c) mv += wo[c] * mu[c];
        float qacc = 0.f;
        for (int i2 = 0; i2 < 32; ++i2) {
            float tt = 0.f;
#pragma unroll
            for (int j2 = 0; j2 < 32; ++j2) tt += wo[j2] * cov[i2 * 32 + j2];
            qacc += wo[i2] * tt;
        }
        const float var = qacc * (1.f / 16384.f) - mv * mv;
        const float A = gamma[tid] * rsqrtf(var + 1e-5f);
        Aout[tid] = A;
        Sout[tid] = beta[tid] - A * mv;
    }
}

// ---------------------------------------------------------------------------
// K3 (MFMA): out = x + A*(wf.pre) + S'.  512 blocks x 32 px (unchanged).
// ---------------------------------------------------------------------------
__global__ __launch_bounds__(256) void k_out(
    const bf16* __restrict__ pre, const u16* __restrict__ wfh,
    const u16* __restrict__ wfl, const float* __restrict__ x,
    const float* __restrict__ A, const float* __restrict__ S,
    float* __restrict__ out)
{
    __shared__ u16 wh[256 * 40];
    __shared__ u16 wl[256 * 40];
    __shared__ u16 pL[32 * 40];
    const int tid = threadIdx.x;
    const int gp0 = blockIdx.x * 32;
    const int b = gp0 >> 12, p0 = gp0 & 4095;

#pragma unroll
    for (int i = 0; i < 4; ++i) {
        const int idx = tid + i * 256;
        const int o = idx >> 2, c8 = idx & 3;
        *(uint4*)&wh[o * 40 + c8 * 8] = *(const uint4*)&wfh[o * 32 + c8 * 8];
        *(uint4*)&wl[o * 40 + c8 * 8] = *(const uint4*)&wfl[o * 32 + c8 * 8];
    }
    if (tid < 128) {
        const int px = tid >> 2, c8 = tid & 3;
        *(uint4*)&pL[px * 40 + c8 * 8] =
            *(const uint4*)&((const u16*)pre)[(gp0 + px) * 32 + c8 * 8];
    }
    __syncthreads();

    const int w = tid >> 6;
    const int lane = tid & 63;
    const int lm = lane & 15, quad = lane >> 4;

    bf16x8 pb[2];
    pb[0] = *(const bf16x8*)&pL[(0 + lm) * 40 + quad * 8];
    pb[1] = *(const bf16x8*)&pL[(16 + lm) * 40 + quad * 8];

    f32x4 acc[4][2];
#pragma unroll
    for (int mm = 0; mm < 4; ++mm) {
        const int orow = w * 64 + mm * 16 + lm;
        const bf16x8 ah = *(const bf16x8*)&wh[orow * 40 + quad * 8];
        const bf16x8 al = *(const bf16x8*)&wl[orow * 40 + quad * 8];
#pragma unroll
        for (int n = 0; n < 2; ++n) {
            f32x4 t = {0.f, 0.f, 0.f, 0.f};
            t = __builtin_amdgcn_mfma_f32_16x16x32_bf16(ah, pb[n], t, 0, 0, 0);
            acc[mm][n] =
                __builtin_amdgcn_mfma_f32_16x16x32_bf16(al, pb[n], t, 0, 0, 0);
        }
    }

#pragma unroll
    for (int mm = 0; mm < 4; ++mm) {
#pragma unroll
        for (int rg = 0; rg < 4; ++rg) {
            const int o = w * 64 + mm * 16 + quad * 4 + rg;
            const float Ao = A[o], So = S[o];
#pragma unroll
            for (int n = 0; n < 2; ++n) {
                const int ga = ((b << 8) + o) * 4096 + p0 + n * 16 + lm;
                out[ga] = x[ga] + Ao * acc[mm][n][rg] + So;
            }
        }
    }
}

extern "C" void kernel_launch(void* const* d_in, const int* in_sizes, int n_in,
                              void* d_out, int out_size, void* d_ws, size_t ws_size,
                              hipStream_t stream)
{
    (void)in_sizes; (void)n_in; (void)out_size; (void)ws_size;
    float* out = (float*)d_out;
    char* ws = (char*)d_ws;

    const float* x      = (const float*)d_in[0];
    const float* vessel = (const float*)d_in[1];
    const float* wk     = (const float*)d_in[2];
    const float* bk     = (const float*)d_in[3];
    const float* wq     = (const float*)d_in[4];
    const float* bq     = (const float*)d_in[5];
    const float* wx     = (const float*)d_in[6];
    const float* bx     = (const float*)d_in[7];
    const float* wf     = (const float*)d_in[8];
    // d_in[9] (bfb) cancels algebraically in training-mode BN — unused.
    const float* gamma  = (const float*)d_in[10];
    const float* beta   = (const float*)d_in[11];

    // Workspace layout — all slots DISJOINT (R2's overlap here was the bug):
    bf16* km  = (bf16*)(ws);                        //       0 .. 1048576
    bf16* qm  = (bf16*)(ws + 1048576);              // 1048576 .. 2097152
    bf16* xm  = (bf16*)(ws + 2097152);              // 2097152 .. 3145728
    bf16* pre = (bf16*)(ws + 3145728);              // 3145728 .. 4194304
    float* partials       = (float*)(ws + 4194304); // 270336 B -> 4464640
    unsigned int* counter = (unsigned int*)(ws + 4464640); // 128 B -> 4464768
    float* Abuf = (float*)(ws + 4465664);           // 1024 B -> 4466688
    float* Sbuf = (float*)(ws + 4466688);           // 1024 B -> 4467712
    u16*   wfh  = (u16*)  (ws + 4467712);           // 16384 B -> 4484096
    u16*   wfl  = (u16*)  (ws + 4484096);           // 16384 B -> 4500480

    k_proj <<< 512, 256, 0, stream>>>(x, vessel, wk, bk, wq, bq, wx, bx,
                                      km, qm, xm, partials, counter);
    k_attn <<<1024, 256, 0, stream>>>(km, qm, xm, pre, partials, counter,
                                      wf, gamma, beta, Abuf, Sbuf, wfh, wfl);
    k_out  <<< 512, 256, 0, stream>>>(pre, wfh, wfl, x, Abuf, Sbuf, out);
}

// Round 5
// 122.312 us; speedup vs baseline: 1.2865x; 1.2865x over previous
//
#include <hip/hip_runtime.h>
#include <hip/hip_bf16.h>

typedef __hip_bfloat16 bf16;
typedef unsigned short u16;
typedef unsigned int u32;

typedef __bf16 bf16x8 __attribute__((ext_vector_type(8)));
typedef float f32x4 __attribute__((ext_vector_type(4)));

__device__ __forceinline__ float bf2f(bf16 v) { return __bfloat162float(v); }
__device__ __forceinline__ float us2f(u16 u) {
    union { u32 i; float f; } c; c.i = ((u32)u) << 16; return c.f;
}
__device__ __forceinline__ u16 f2u(float f) {
    union { bf16 b; u16 u; } c; c.b = __float2bfloat16(f); return c.u;
}

// ---------------------------------------------------------------------------
// K1 (MFMA GEMM): km/qm/xm = conv1x1. Blocks 0..63 zero the covariance
// partials arena (R1-proven structure).
// ---------------------------------------------------------------------------
__global__ __launch_bounds__(256) void k_proj(
    const float* __restrict__ x, const float* __restrict__ vessel,
    const float* __restrict__ wk, const float* __restrict__ bk,
    const float* __restrict__ wq, const float* __restrict__ bq,
    const float* __restrict__ wx, const float* __restrict__ bx,
    bf16* __restrict__ km, bf16* __restrict__ qm, bf16* __restrict__ xm,
    float* __restrict__ partials)
{
    __shared__ u16 xs[64 * 264];
    __shared__ u16 wsh[48 * 264];
    const int tid = threadIdx.x;
    const int bid = blockIdx.x;
    const int nh = bid & 1;
    const int pt = bid >> 1;
    const int b  = pt >> 6;
    const int p0 = (pt & 63) * 64;

    if (bid < 64) {
#pragma unroll
        for (int i = 0; i < 5; ++i) {
            const int idx = tid + i * 256;
            if (idx < 1056) partials[bid * 1056 + idx] = 0.f;
        }
    }

#pragma unroll
    for (int i = 0; i < 16; ++i) {
        const int idx4 = tid + i * 256;
        const int ch = idx4 >> 4;
        const int px4 = (idx4 & 15) * 4;
        const float4 v = *(const float4*)&x[(b * 256 + ch) * 4096 + p0 + px4];
        xs[(px4 + 0) * 264 + ch] = f2u(v.x);
        xs[(px4 + 1) * 264 + ch] = f2u(v.y);
        xs[(px4 + 2) * 264 + ch] = f2u(v.z);
        xs[(px4 + 3) * 264 + ch] = f2u(v.w);
    }
#pragma unroll
    for (int i = 0; i < 12; ++i) {
        const int idx4 = tid + i * 256;
        const int o = idx4 >> 6;
        const int ch4 = (idx4 & 63) * 4;
        const int go = nh * 48 + o;
        const float* wp = (go < 32) ? wk : ((go < 64) ? wq : wx);
        const float4 v = *(const float4*)&wp[(go & 31) * 256 + ch4];
        wsh[o * 264 + ch4 + 0] = f2u(v.x);
        wsh[o * 264 + ch4 + 1] = f2u(v.y);
        wsh[o * 264 + ch4 + 2] = f2u(v.z);
        wsh[o * 264 + ch4 + 3] = f2u(v.w);
    }
    __syncthreads();

    const int w = tid >> 6;
    const int lane = tid & 63;
    const int lm = lane & 15, quad = lane >> 4;

    f32x4 acc0 = {0.f, 0.f, 0.f, 0.f};
    f32x4 acc1 = {0.f, 0.f, 0.f, 0.f};
    f32x4 acc2 = {0.f, 0.f, 0.f, 0.f};
#pragma unroll
    for (int kk = 0; kk < 8; ++kk) {
        const int k0 = kk * 32 + quad * 8;
        const bf16x8 a  = *(const bf16x8*)&xs[(w * 16 + lm) * 264 + k0];
        const bf16x8 b0 = *(const bf16x8*)&wsh[(0 + lm) * 264 + k0];
        const bf16x8 b1 = *(const bf16x8*)&wsh[(16 + lm) * 264 + k0];
        const bf16x8 b2 = *(const bf16x8*)&wsh[(32 + lm) * 264 + k0];
        acc0 = __builtin_amdgcn_mfma_f32_16x16x32_bf16(a, b0, acc0, 0, 0, 0);
        acc1 = __builtin_amdgcn_mfma_f32_16x16x32_bf16(a, b1, acc1, 0, 0, 0);
        acc2 = __builtin_amdgcn_mfma_f32_16x16x32_bf16(a, b2, acc2, 0, 0, 0);
    }
#pragma unroll
    for (int t = 0; t < 3; ++t) {
        const f32x4 acc = (t == 0) ? acc0 : ((t == 1) ? acc1 : acc2);
        const int go = nh * 48 + t * 16 + lm;
        const float* bs = (go < 32) ? bk : ((go < 64) ? bq : bx);
        const float bias = bs[go & 31];
        bf16* dst = (go < 32) ? km : ((go < 64) ? qm : xm);
#pragma unroll
        for (int rg = 0; rg < 4; ++rg) {
            const int px = p0 + w * 16 + quad * 4 + rg;
            float vv = acc[rg] + bias;
            if (go < 32) vv *= vessel[b * 4096 + px];
            dst[(b * 4096 + px) * 32 + (go & 31)] = __float2bfloat16(vv);
        }
    }
}

// ---------------------------------------------------------------------------
// K2 (MFMA): 4-scale local attention. R1-proven shape: block = 4x8 px tile
// (32 px), grid 512, LDS 53248 B -> 3 blocks/CU, Q fragments from global.
// Cov partial: symmetric -> wave 2's tile (1,0) is the transpose of wave 1's
// (0,1); it is SKIPPED here (-256 atomics/block) and reconstructed in k_stats.
// ---------------------------------------------------------------------------
__global__ __launch_bounds__(256, 3) void k_attn(
    const bf16* __restrict__ km, const bf16* __restrict__ qm,
    const bf16* __restrict__ xm, bf16* __restrict__ pre,
    float* __restrict__ partials)
{
    __shared__ u16 kT[192 * 40];     // 15360 B; reused as P[32*200] after S
    __shared__ u16 xTt[32 * 200];    // 12800 B  [ch][pos]
    __shared__ float S[32 * 196];    // 25088 B  [px][pos]; reused as preT
    u16* P = kT;                     // P[px*200+pos] (kT dead after Phase A)
    u16* preT = (u16*)S;             // preT[ch*40+px] (S dead after Phase B)

    const int tid = threadIdx.x;
    const int b = blockIdx.x >> 7;
    const int t128 = blockIdx.x & 127;
    const int h0 = (t128 >> 3) * 4;          // 16 row-tiles of 4
    const int w0 = (t128 & 7) * 8;           // 8 col-tiles of 8
    const u16* uk = (const u16*)km;
    const u16* ux = (const u16*)xm;
    const u16* uq = (const u16*)qm;
    const uint4 z4 = {0u, 0u, 0u, 0u};

    // stage kT [pos][ch] + xTt [ch][pos] (transposed): 192 pos x 4 c8
#pragma unroll
    for (int i = 0; i < 3; ++i) {
        const int idx4 = tid + i * 256;      // 0..767
        const int pos = idx4 >> 2, c8 = idx4 & 3;
        const int gh = h0 - 4 + (pos >> 4), gw = w0 - 4 + (pos & 15);
        uint4 kv = z4, xv = z4;
        if (gh >= 0 && gh < 64 && gw >= 0 && gw < 64) {
            const int g = ((b << 12) + (gh << 6) + gw) * 32 + c8 * 8;
            kv = *(const uint4*)&uk[g];
            xv = *(const uint4*)&ux[g];
        }
        *(uint4*)&kT[pos * 40 + c8 * 8] = kv;
        const u16* xu = (const u16*)&xv;
#pragma unroll
        for (int t = 0; t < 8; ++t)
            xTt[(c8 * 8 + t) * 200 + pos] = xu[t];
    }
    __syncthreads();

    const int w = tid >> 6;
    const int lane = tid & 63;
    const int lm = lane & 15, quad = lane >> 4;

    // Phase A: S tiles. 24 tiles (m 0..1, n 0..11), wave w takes t=w+4i.
#pragma unroll
    for (int i = 0; i < 6; ++i) {
        const int t = w + i * 4;
        const int m = t / 12, n = t - m * 12;
        const int am = m * 16 + lm;
        const int qgh = h0 + (am >> 3), qgw = w0 + (am & 7);
        const bf16x8 a =
            *(const bf16x8*)&uq[(((b << 12) + (qgh << 6) + qgw) << 5) + quad * 8];
        const bf16x8 bb = *(const bf16x8*)&kT[(n * 16 + lm) * 40 + quad * 8];
        f32x4 acc = {0.f, 0.f, 0.f, 0.f};
        acc = __builtin_amdgcn_mfma_f32_16x16x32_bf16(a, bb, acc, 0, 0, 0);
#pragma unroll
        for (int rg = 0; rg < 4; ++rg)
            S[(m * 16 + quad * 4 + rg) * 196 + n * 16 + lm] = acc[rg];
    }
    __syncthreads();

    // Phase B: per-thread 24 positions of one pixel
    const int px = tid >> 3, cg = tid & 7;
    const int ty = px >> 3, tx = px & 7;
    float e[24];
    float Z3 = 0.f, Z5 = 0.f, Z7 = 0.f, Z9 = 0.f;
#pragma unroll
    for (int i = 0; i < 24; ++i) {
        const int pos = cg + 8 * i;
        const int hy = pos >> 4, hx = pos & 15;
        const int dy = hy - 4 - ty, dx = hx - 4 - tx;
        const int ady = dy < 0 ? -dy : dy, adx = dx < 0 ? -dx : dx;
        const int r = ady > adx ? ady : adx;
        const float s = S[px * 196 + pos];
        const float ev = (r <= 4) ? __expf(s) : 0.f;
        e[i] = ev;
        if (r <= 1) Z3 += ev;
        if (r <= 2) Z5 += ev;
        if (r <= 3) Z7 += ev;
        Z9 += ev;
    }
#pragma unroll
    for (int m = 1; m <= 4; m <<= 1) {
        Z3 += __shfl_xor(Z3, m);
        Z5 += __shfl_xor(Z5, m);
        Z7 += __shfl_xor(Z7, m);
        Z9 += __shfl_xor(Z9, m);
    }
    const float iZ3 = 1.f / Z3, iZ5 = 1.f / Z5, iZ7 = 1.f / Z7, iZ9 = 1.f / Z9;
#pragma unroll
    for (int i = 0; i < 24; ++i) {
        const int pos = cg + 8 * i;
        const int hy = pos >> 4, hx = pos & 15;
        const int dy = hy - 4 - ty, dx = hx - 4 - tx;
        const int ady = dy < 0 ? -dy : dy, adx = dx < 0 ? -dx : dx;
        const int r = ady > adx ? ady : adx;
        float coef = iZ9;
        if (r <= 1) coef += iZ3;
        if (r <= 2) coef += iZ5;
        if (r <= 3) coef += iZ7;
        P[px * 200 + pos] = f2u(e[i] * coef);
    }
    __syncthreads();

    // Phase C: pre(32x32) = P(32x192) . X^T : wave w -> tile (m0,n0)
    const int m0 = w >> 1, n0 = w & 1;
    f32x4 acc = {0.f, 0.f, 0.f, 0.f};
#pragma unroll
    for (int kk = 0; kk < 6; ++kk) {
        const int k0 = kk * 32 + quad * 8;
        const bf16x8 a = *(const bf16x8*)&P[(m0 * 16 + lm) * 200 + k0];
        const bf16x8 bb = *(const bf16x8*)&xTt[(n0 * 16 + lm) * 200 + k0];
        acc = __builtin_amdgcn_mfma_f32_16x16x32_bf16(a, bb, acc, 0, 0, 0);
    }
#pragma unroll
    for (int rg = 0; rg < 4; ++rg) {
        const int pl = m0 * 16 + quad * 4 + rg;
        const int gh = h0 + (pl >> 3), gw = w0 + (pl & 7);
        pre[(((b << 12) + (gh << 6) + gw) << 5) + n0 * 16 + lm] =
            __float2bfloat16(acc[rg]);
        // transposed bf16 copy for the covariance MFMA: preT[ch][px]
        preT[(n0 * 16 + lm) * 40 + pl] = f2u(acc[rg]);
    }
    __syncthreads();

    // Covariance partial: cov[i][j] += sum_px preT[i][px]*preT[j][px]
    // Symmetric: skip wave 2's tile (1,0) (transpose of wave 1's (0,1)).
    const int it = w >> 1, jt = w & 1;
    if (w != 2) {
        const bf16x8 ca = *(const bf16x8*)&preT[(it * 16 + lm) * 40 + quad * 8];
        const bf16x8 cb = *(const bf16x8*)&preT[(jt * 16 + lm) * 40 + quad * 8];
        f32x4 cacc = {0.f, 0.f, 0.f, 0.f};
        cacc = __builtin_amdgcn_mfma_f32_16x16x32_bf16(ca, cb, cacc, 0, 0, 0);
        float* pslot = &partials[(blockIdx.x & 63) * 1056];
#pragma unroll
        for (int rg = 0; rg < 4; ++rg) {
            const int ii = it * 16 + quad * 4 + rg, jj = jt * 16 + lm;
            atomicAdd(&pslot[ii * 32 + jj], cacc[rg]);
        }
    }
    // Per-channel sums: 128 threads, 4 segments of 8 px each, shfl-reduce.
    if (tid < 128) {
        float* pslot = &partials[(blockIdx.x & 63) * 1056];
        const int cc = tid >> 2, sg = tid & 3;
        float s = 0.f;
#pragma unroll
        for (int p = 0; p < 8; ++p) s += us2f(preT[cc * 40 + sg * 8 + p]);
        s += __shfl_xor(s, 1);
        s += __shfl_xor(s, 2);
        if (sg == 0) atomicAdd(&pslot[1024 + cc], s);
    }
}

// ---------------------------------------------------------------------------
// K2c: BN constants. bfb cancels in training-mode BN:
//   out = x + A*(wf.pre) + (beta - A*mv).  Emits wf split into bf16 hi/lo.
// Cov's lower-left 16x16 tile was skipped in k_attn (symmetry) — rebuilt
// here from the upper-right tile (disjoint read/write addresses, race-free).
// ---------------------------------------------------------------------------
__global__ __launch_bounds__(256) void k_stats(
    const float* __restrict__ partials, const float* __restrict__ wf,
    const float* __restrict__ gamma, const float* __restrict__ beta,
    float* __restrict__ Aout, float* __restrict__ Sout,
    u16* __restrict__ wfh, u16* __restrict__ wfl)
{
    __shared__ float cov[1024];
    __shared__ float mu[32];
    const int tid = threadIdx.x;
    float4 a = {0.f, 0.f, 0.f, 0.f};
    for (int blk = 0; blk < 64; ++blk) {
        const float4 p = *(const float4*)&partials[blk * 1056 + tid * 4];
        a.x += p.x; a.y += p.y; a.z += p.z; a.w += p.w;
    }
    *(float4*)&cov[tid * 4] = a;
    if (tid < 32) {
        float s = 0.f;
        for (int blk = 0; blk < 64; ++blk) s += partials[blk * 1056 + 1024 + tid];
        mu[tid] = s * (1.f / 16384.f);
    }
    __syncthreads();
    // symmetry fixup: cov[i>=16][j<16] = cov[j][i] (reads upper-right,
    // writes lower-left — disjoint address sets across all 256 threads)
    {
        const int fi = 16 + (tid >> 4), fj = tid & 15;
        cov[fi * 32 + fj] = cov[fj * 32 + fi];
    }
    __syncthreads();

    float wo[32];
#pragma unroll
    for (int c = 0; c < 32; ++c) wo[c] = wf[tid * 32 + c];

    // emit bf16 hi/lo split of this thread's wf row
    __attribute__((aligned(16))) u16 hb[32];
    __attribute__((aligned(16))) u16 lb[32];
#pragma unroll
    for (int c = 0; c < 32; ++c) {
        const float v = wo[c];
        const u16 h = f2u(v);
        hb[c] = h;
        lb[c] = f2u(v - us2f(h));
    }
#pragma unroll
    for (int c8 = 0; c8 < 4; ++c8) {
        *(uint4*)&wfh[tid * 32 + c8 * 8] = *(const uint4*)&hb[c8 * 8];
        *(uint4*)&wfl[tid * 32 + c8 * 8] = *(const uint4*)&lb[c8 * 8];
    }

    float mv = 0.f;
#pragma unroll
    for (int c = 0; c < 32; ++c) mv += wo[c] * mu[c];
    float qacc = 0.f;
    for (int i2 = 0; i2 < 32; ++i2) {
        float t = 0.f;
#pragma unroll
        for (int j2 = 0; j2 < 32; ++j2) t += wo[j2] * cov[i2 * 32 + j2];
        qacc += wo[i2] * t;
    }
    const float var = qacc * (1.f / 16384.f) - mv * mv;
    const float A = gamma[tid] * rsqrtf(var + 1e-5f);
    Aout[tid] = A;
    Sout[tid] = beta[tid] - A * mv;
}

// ---------------------------------------------------------------------------
// K3 (MFMA): out = x + A*(wf.pre) + S'.  512 blocks x 32 px (R1-proven).
// ---------------------------------------------------------------------------
__global__ __launch_bounds__(256) void k_out(
    const bf16* __restrict__ pre, const u16* __restrict__ wfh,
    const u16* __restrict__ wfl, const float* __restrict__ x,
    const float* __restrict__ A, const float* __restrict__ S,
    float* __restrict__ out)
{
    __shared__ u16 wh[256 * 40];
    __shared__ u16 wl[256 * 40];
    __shared__ u16 pL[32 * 40];
    const int tid = threadIdx.x;
    const int gp0 = blockIdx.x * 32;
    const int b = gp0 >> 12, p0 = gp0 & 4095;

#pragma unroll
    for (int i = 0; i < 4; ++i) {
        const int idx = tid + i * 256;
        const int o = idx >> 2, c8 = idx & 3;
        *(uint4*)&wh[o * 40 + c8 * 8] = *(const uint4*)&wfh[o * 32 + c8 * 8];
        *(uint4*)&wl[o * 40 + c8 * 8] = *(const uint4*)&wfl[o * 32 + c8 * 8];
    }
    if (tid < 128) {
        const int px = tid >> 2, c8 = tid & 3;
        *(uint4*)&pL[px * 40 + c8 * 8] =
            *(const uint4*)&((const u16*)pre)[(gp0 + px) * 32 + c8 * 8];
    }
    __syncthreads();

    const int w = tid >> 6;
    const int lane = tid & 63;
    const int lm = lane & 15, quad = lane >> 4;

    bf16x8 pb[2];
    pb[0] = *(const bf16x8*)&pL[(0 + lm) * 40 + quad * 8];
    pb[1] = *(const bf16x8*)&pL[(16 + lm) * 40 + quad * 8];

    f32x4 acc[4][2];
#pragma unroll
    for (int mm = 0; mm < 4; ++mm) {
        const int orow = w * 64 + mm * 16 + lm;
        const bf16x8 ah = *(const bf16x8*)&wh[orow * 40 + quad * 8];
        const bf16x8 al = *(const bf16x8*)&wl[orow * 40 + quad * 8];
#pragma unroll
        for (int n = 0; n < 2; ++n) {
            f32x4 t = {0.f, 0.f, 0.f, 0.f};
            t = __builtin_amdgcn_mfma_f32_16x16x32_bf16(ah, pb[n], t, 0, 0, 0);
            acc[mm][n] =
                __builtin_amdgcn_mfma_f32_16x16x32_bf16(al, pb[n], t, 0, 0, 0);
        }
    }

#pragma unroll
    for (int mm = 0; mm < 4; ++mm) {
#pragma unroll
        for (int rg = 0; rg < 4; ++rg) {
            const int o = w * 64 + mm * 16 + quad * 4 + rg;
            const float Ao = A[o], So = S[o];
#pragma unroll
            for (int n = 0; n < 2; ++n) {
                const int ga = ((b << 8) + o) * 4096 + p0 + n * 16 + lm;
                out[ga] = x[ga] + Ao * acc[mm][n][rg] + So;
            }
        }
    }
}

extern "C" void kernel_launch(void* const* d_in, const int* in_sizes, int n_in,
                              void* d_out, int out_size, void* d_ws, size_t ws_size,
                              hipStream_t stream)
{
    (void)in_sizes; (void)n_in; (void)out_size; (void)ws_size;
    float* out = (float*)d_out;
    char* ws = (char*)d_ws;

    const float* x      = (const float*)d_in[0];
    const float* vessel = (const float*)d_in[1];
    const float* wk     = (const float*)d_in[2];
    const float* bk     = (const float*)d_in[3];
    const float* wq     = (const float*)d_in[4];
    const float* bq     = (const float*)d_in[5];
    const float* wx     = (const float*)d_in[6];
    const float* bx     = (const float*)d_in[7];
    const float* wf     = (const float*)d_in[8];
    // d_in[9] (bfb) cancels algebraically in training-mode BN — unused.
    const float* gamma  = (const float*)d_in[10];
    const float* beta   = (const float*)d_in[11];

    // R1-proven disjoint workspace layout:
    bf16* km  = (bf16*)(ws);
    bf16* qm  = (bf16*)(ws + 1048576);
    bf16* xm  = (bf16*)(ws + 2097152);
    bf16* pre = (bf16*)(ws + 3145728);
    float* partials = (float*)(ws + 4194304);   // 64*1056*4 = 270336 B
    float* Abuf     = (float*)(ws + 4464640);
    float* Sbuf     = (float*)(ws + 4465664);
    u16*   wfh      = (u16*)  (ws + 4466688);   // 16384 B
    u16*   wfl      = (u16*)  (ws + 4483072);   // 16384 B

    k_proj <<<512, 256, 0, stream>>>(x, vessel, wk, bk, wq, bq, wx, bx,
                                     km, qm, xm, partials);
    k_attn <<<512, 256, 0, stream>>>(km, qm, xm, pre, partials);
    k_stats<<<  1, 256, 0, stream>>>(partials, wf, gamma, beta, Abuf, Sbuf,
                                     wfh, wfl);
    k_out  <<<512, 256, 0, stream>>>(pre, wfh, wfl, x, Abuf, Sbuf, out);
}

// Round 6
// 120.221 us; speedup vs baseline: 1.3088x; 1.0174x over previous
//
#include <hip/hip_runtime.h>
#include <hip/hip_bf16.h>

typedef __hip_bfloat16 bf16;
typedef unsigned short u16;
typedef unsigned int u32;

typedef __bf16 bf16x8 __attribute__((ext_vector_type(8)));
typedef float f32x4 __attribute__((ext_vector_type(4)));

__device__ __forceinline__ float bf2f(bf16 v) { return __bfloat162float(v); }
__device__ __forceinline__ float us2f(u16 u) {
    union { u32 i; float f; } c; c.i = ((u32)u) << 16; return c.f;
}
__device__ __forceinline__ u16 f2u(float f) {
    union { bf16 b; u16 u; } c; c.b = __float2bfloat16(f); return c.u;
}

// ---------------------------------------------------------------------------
// K1 (MFMA GEMM): km/qm/xm = conv1x1. Blocks 0..63 zero the covariance
// partials arena. (R5-proven, unchanged.)
// ---------------------------------------------------------------------------
__global__ __launch_bounds__(256) void k_proj(
    const float* __restrict__ x, const float* __restrict__ vessel,
    const float* __restrict__ wk, const float* __restrict__ bk,
    const float* __restrict__ wq, const float* __restrict__ bq,
    const float* __restrict__ wx, const float* __restrict__ bx,
    bf16* __restrict__ km, bf16* __restrict__ qm, bf16* __restrict__ xm,
    float* __restrict__ partials)
{
    __shared__ u16 xs[64 * 264];
    __shared__ u16 wsh[48 * 264];
    const int tid = threadIdx.x;
    const int bid = blockIdx.x;
    const int nh = bid & 1;
    const int pt = bid >> 1;
    const int b  = pt >> 6;
    const int p0 = (pt & 63) * 64;

    if (bid < 64) {
#pragma unroll
        for (int i = 0; i < 5; ++i) {
            const int idx = tid + i * 256;
            if (idx < 1056) partials[bid * 1056 + idx] = 0.f;
        }
    }

#pragma unroll
    for (int i = 0; i < 16; ++i) {
        const int idx4 = tid + i * 256;
        const int ch = idx4 >> 4;
        const int px4 = (idx4 & 15) * 4;
        const float4 v = *(const float4*)&x[(b * 256 + ch) * 4096 + p0 + px4];
        xs[(px4 + 0) * 264 + ch] = f2u(v.x);
        xs[(px4 + 1) * 264 + ch] = f2u(v.y);
        xs[(px4 + 2) * 264 + ch] = f2u(v.z);
        xs[(px4 + 3) * 264 + ch] = f2u(v.w);
    }
#pragma unroll
    for (int i = 0; i < 12; ++i) {
        const int idx4 = tid + i * 256;
        const int o = idx4 >> 6;
        const int ch4 = (idx4 & 63) * 4;
        const int go = nh * 48 + o;
        const float* wp = (go < 32) ? wk : ((go < 64) ? wq : wx);
        const float4 v = *(const float4*)&wp[(go & 31) * 256 + ch4];
        wsh[o * 264 + ch4 + 0] = f2u(v.x);
        wsh[o * 264 + ch4 + 1] = f2u(v.y);
        wsh[o * 264 + ch4 + 2] = f2u(v.z);
        wsh[o * 264 + ch4 + 3] = f2u(v.w);
    }
    __syncthreads();

    const int w = tid >> 6;
    const int lane = tid & 63;
    const int lm = lane & 15, quad = lane >> 4;

    f32x4 acc0 = {0.f, 0.f, 0.f, 0.f};
    f32x4 acc1 = {0.f, 0.f, 0.f, 0.f};
    f32x4 acc2 = {0.f, 0.f, 0.f, 0.f};
#pragma unroll
    for (int kk = 0; kk < 8; ++kk) {
        const int k0 = kk * 32 + quad * 8;
        const bf16x8 a  = *(const bf16x8*)&xs[(w * 16 + lm) * 264 + k0];
        const bf16x8 b0 = *(const bf16x8*)&wsh[(0 + lm) * 264 + k0];
        const bf16x8 b1 = *(const bf16x8*)&wsh[(16 + lm) * 264 + k0];
        const bf16x8 b2 = *(const bf16x8*)&wsh[(32 + lm) * 264 + k0];
        acc0 = __builtin_amdgcn_mfma_f32_16x16x32_bf16(a, b0, acc0, 0, 0, 0);
        acc1 = __builtin_amdgcn_mfma_f32_16x16x32_bf16(a, b1, acc1, 0, 0, 0);
        acc2 = __builtin_amdgcn_mfma_f32_16x16x32_bf16(a, b2, acc2, 0, 0, 0);
    }
#pragma unroll
    for (int t = 0; t < 3; ++t) {
        const f32x4 acc = (t == 0) ? acc0 : ((t == 1) ? acc1 : acc2);
        const int go = nh * 48 + t * 16 + lm;
        const float* bs = (go < 32) ? bk : ((go < 64) ? bq : bx);
        const float bias = bs[go & 31];
        bf16* dst = (go < 32) ? km : ((go < 64) ? qm : xm);
#pragma unroll
        for (int rg = 0; rg < 4; ++rg) {
            const int px = p0 + w * 16 + quad * 4 + rg;
            float vv = acc[rg] + bias;
            if (go < 32) vv *= vessel[b * 4096 + px];
            dst[(b * 4096 + px) * 32 + (go & 31)] = __float2bfloat16(vv);
        }
    }
}

// ---------------------------------------------------------------------------
// K2 (MFMA): 4-scale local attention. (R5-proven, unchanged.)
// Block = 4x8 px tile, grid 512, LDS 53248 B, Q fragments from global.
// Cov partial: symmetric -> wave 2's tile (1,0) skipped, rebuilt in k_out.
// ---------------------------------------------------------------------------
__global__ __launch_bounds__(256, 3) void k_attn(
    const bf16* __restrict__ km, const bf16* __restrict__ qm,
    const bf16* __restrict__ xm, bf16* __restrict__ pre,
    float* __restrict__ partials)
{
    __shared__ u16 kT[192 * 40];     // 15360 B; reused as P[32*200] after S
    __shared__ u16 xTt[32 * 200];    // 12800 B  [ch][pos]
    __shared__ float S[32 * 196];    // 25088 B  [px][pos]; reused as preT
    u16* P = kT;                     // P[px*200+pos] (kT dead after Phase A)
    u16* preT = (u16*)S;             // preT[ch*40+px] (S dead after Phase B)

    const int tid = threadIdx.x;
    const int b = blockIdx.x >> 7;
    const int t128 = blockIdx.x & 127;
    const int h0 = (t128 >> 3) * 4;          // 16 row-tiles of 4
    const int w0 = (t128 & 7) * 8;           // 8 col-tiles of 8
    const u16* uk = (const u16*)km;
    const u16* ux = (const u16*)xm;
    const u16* uq = (const u16*)qm;
    const uint4 z4 = {0u, 0u, 0u, 0u};

    // stage kT [pos][ch] + xTt [ch][pos] (transposed): 192 pos x 4 c8
#pragma unroll
    for (int i = 0; i < 3; ++i) {
        const int idx4 = tid + i * 256;      // 0..767
        const int pos = idx4 >> 2, c8 = idx4 & 3;
        const int gh = h0 - 4 + (pos >> 4), gw = w0 - 4 + (pos & 15);
        uint4 kv = z4, xv = z4;
        if (gh >= 0 && gh < 64 && gw >= 0 && gw < 64) {
            const int g = ((b << 12) + (gh << 6) + gw) * 32 + c8 * 8;
            kv = *(const uint4*)&uk[g];
            xv = *(const uint4*)&ux[g];
        }
        *(uint4*)&kT[pos * 40 + c8 * 8] = kv;
        const u16* xu = (const u16*)&xv;
#pragma unroll
        for (int t = 0; t < 8; ++t)
            xTt[(c8 * 8 + t) * 200 + pos] = xu[t];
    }
    __syncthreads();

    const int w = tid >> 6;
    const int lane = tid & 63;
    const int lm = lane & 15, quad = lane >> 4;

    // Phase A: S tiles. 24 tiles (m 0..1, n 0..11), wave w takes t=w+4i.
#pragma unroll
    for (int i = 0; i < 6; ++i) {
        const int t = w + i * 4;
        const int m = t / 12, n = t - m * 12;
        const int am = m * 16 + lm;
        const int qgh = h0 + (am >> 3), qgw = w0 + (am & 7);
        const bf16x8 a =
            *(const bf16x8*)&uq[(((b << 12) + (qgh << 6) + qgw) << 5) + quad * 8];
        const bf16x8 bb = *(const bf16x8*)&kT[(n * 16 + lm) * 40 + quad * 8];
        f32x4 acc = {0.f, 0.f, 0.f, 0.f};
        acc = __builtin_amdgcn_mfma_f32_16x16x32_bf16(a, bb, acc, 0, 0, 0);
#pragma unroll
        for (int rg = 0; rg < 4; ++rg)
            S[(m * 16 + quad * 4 + rg) * 196 + n * 16 + lm] = acc[rg];
    }
    __syncthreads();

    // Phase B: per-thread 24 positions of one pixel
    const int px = tid >> 3, cg = tid & 7;
    const int ty = px >> 3, tx = px & 7;
    float e[24];
    float Z3 = 0.f, Z5 = 0.f, Z7 = 0.f, Z9 = 0.f;
#pragma unroll
    for (int i = 0; i < 24; ++i) {
        const int pos = cg + 8 * i;
        const int hy = pos >> 4, hx = pos & 15;
        const int dy = hy - 4 - ty, dx = hx - 4 - tx;
        const int ady = dy < 0 ? -dy : dy, adx = dx < 0 ? -dx : dx;
        const int r = ady > adx ? ady : adx;
        const float s = S[px * 196 + pos];
        const float ev = (r <= 4) ? __expf(s) : 0.f;
        e[i] = ev;
        if (r <= 1) Z3 += ev;
        if (r <= 2) Z5 += ev;
        if (r <= 3) Z7 += ev;
        Z9 += ev;
    }
#pragma unroll
    for (int m = 1; m <= 4; m <<= 1) {
        Z3 += __shfl_xor(Z3, m);
        Z5 += __shfl_xor(Z5, m);
        Z7 += __shfl_xor(Z7, m);
        Z9 += __shfl_xor(Z9, m);
    }
    const float iZ3 = 1.f / Z3, iZ5 = 1.f / Z5, iZ7 = 1.f / Z7, iZ9 = 1.f / Z9;
#pragma unroll
    for (int i = 0; i < 24; ++i) {
        const int pos = cg + 8 * i;
        const int hy = pos >> 4, hx = pos & 15;
        const int dy = hy - 4 - ty, dx = hx - 4 - tx;
        const int ady = dy < 0 ? -dy : dy, adx = dx < 0 ? -dx : dx;
        const int r = ady > adx ? ady : adx;
        float coef = iZ9;
        if (r <= 1) coef += iZ3;
        if (r <= 2) coef += iZ5;
        if (r <= 3) coef += iZ7;
        P[px * 200 + pos] = f2u(e[i] * coef);
    }
    __syncthreads();

    // Phase C: pre(32x32) = P(32x192) . X^T : wave w -> tile (m0,n0)
    const int m0 = w >> 1, n0 = w & 1;
    f32x4 acc = {0.f, 0.f, 0.f, 0.f};
#pragma unroll
    for (int kk = 0; kk < 6; ++kk) {
        const int k0 = kk * 32 + quad * 8;
        const bf16x8 a = *(const bf16x8*)&P[(m0 * 16 + lm) * 200 + k0];
        const bf16x8 bb = *(const bf16x8*)&xTt[(n0 * 16 + lm) * 200 + k0];
        acc = __builtin_amdgcn_mfma_f32_16x16x32_bf16(a, bb, acc, 0, 0, 0);
    }
#pragma unroll
    for (int rg = 0; rg < 4; ++rg) {
        const int pl = m0 * 16 + quad * 4 + rg;
        const int gh = h0 + (pl >> 3), gw = w0 + (pl & 7);
        pre[(((b << 12) + (gh << 6) + gw) << 5) + n0 * 16 + lm] =
            __float2bfloat16(acc[rg]);
        // transposed bf16 copy for the covariance MFMA: preT[ch][px]
        preT[(n0 * 16 + lm) * 40 + pl] = f2u(acc[rg]);
    }
    __syncthreads();

    // Covariance partial: cov[i][j] += sum_px preT[i][px]*preT[j][px]
    // Symmetric: skip wave 2's tile (1,0) (transpose of wave 1's (0,1)).
    const int it = w >> 1, jt = w & 1;
    if (w != 2) {
        const bf16x8 ca = *(const bf16x8*)&preT[(it * 16 + lm) * 40 + quad * 8];
        const bf16x8 cb = *(const bf16x8*)&preT[(jt * 16 + lm) * 40 + quad * 8];
        f32x4 cacc = {0.f, 0.f, 0.f, 0.f};
        cacc = __builtin_amdgcn_mfma_f32_16x16x32_bf16(ca, cb, cacc, 0, 0, 0);
        float* pslot = &partials[(blockIdx.x & 63) * 1056];
#pragma unroll
        for (int rg = 0; rg < 4; ++rg) {
            const int ii = it * 16 + quad * 4 + rg, jj = jt * 16 + lm;
            atomicAdd(&pslot[ii * 32 + jj], cacc[rg]);
        }
    }
    // Per-channel sums: 128 threads, 4 segments of 8 px each, shfl-reduce.
    if (tid < 128) {
        float* pslot = &partials[(blockIdx.x & 63) * 1056];
        const int cc = tid >> 2, sg = tid & 3;
        float s = 0.f;
#pragma unroll
        for (int p = 0; p < 8; ++p) s += us2f(preT[cc * 40 + sg * 8 + p]);
        s += __shfl_xor(s, 1);
        s += __shfl_xor(s, 2);
        if (sg == 0) atomicAdd(&pslot[1024 + cc], s);
    }
}

// ---------------------------------------------------------------------------
// K3 (MFMA, fused stats): out = x + A*(wf.pre) + S'.  512 blocks x 32 px.
// Each block redundantly computes the BN constants from the atomic partials
// (visible here via the kernel boundary — no agent-scope loads needed):
// 256 KB L2/L3-hot reduce + symmetric-cov fixup + 1K-FMA quadratic form per
// thread, ~1-2 us fully parallel across blocks. Replaces the 1-block k_stats
// launch (which idled 255 CUs) and the wfh/wfl global round-trip: the wf
// hi/lo bf16 split now happens during staging.
// ---------------------------------------------------------------------------
__global__ __launch_bounds__(256) void k_out(
    const bf16* __restrict__ pre, const float* __restrict__ wf,
    const float* __restrict__ partials, const float* __restrict__ gamma,
    const float* __restrict__ beta, const float* __restrict__ x,
    float* __restrict__ out)
{
    __shared__ u16 wh[256 * 40];   // 20480 B [out][ch] bf16-hi
    __shared__ u16 wl[256 * 40];   // 20480 B bf16-lo
    __shared__ u16 pL[32 * 40];    //  2560 B [px][ch]
    __shared__ float cov[1024];    //  4096 B
    __shared__ float mu[32];
    __shared__ float As[256];
    __shared__ float Ss[256];
    const int tid = threadIdx.x;
    const int gp0 = blockIdx.x * 32;
    const int b = gp0 >> 12, p0 = gp0 & 4095;

    // stage wf (f32) -> hi/lo bf16 LDS, 2048 float4 over 256 threads
#pragma unroll
    for (int i = 0; i < 8; ++i) {
        const int idx = tid + i * 256;       // 0..2047
        const int o = idx >> 3, c4 = idx & 7;
        const float4 v = *(const float4*)&wf[o * 32 + c4 * 4];
        ushort4 hv, lv;
        hv.x = f2u(v.x); lv.x = f2u(v.x - us2f(hv.x));
        hv.y = f2u(v.y); lv.y = f2u(v.y - us2f(hv.y));
        hv.z = f2u(v.z); lv.z = f2u(v.z - us2f(hv.z));
        hv.w = f2u(v.w); lv.w = f2u(v.w - us2f(hv.w));
        *(ushort4*)&wh[o * 40 + c4 * 4] = hv;
        *(ushort4*)&wl[o * 40 + c4 * 4] = lv;
    }
    if (tid < 128) {
        const int px = tid >> 2, c8 = tid & 3;
        *(uint4*)&pL[px * 40 + c8 * 8] =
            *(const uint4*)&((const u16*)pre)[(gp0 + px) * 32 + c8 * 8];
    }
    // reduce covariance partials (64 slots x 1056), L2/L3-resident
    {
        float4 a4 = {0.f, 0.f, 0.f, 0.f};
        for (int blk = 0; blk < 64; ++blk) {
            const float4 p = *(const float4*)&partials[blk * 1056 + tid * 4];
            a4.x += p.x; a4.y += p.y; a4.z += p.z; a4.w += p.w;
        }
        *(float4*)&cov[tid * 4] = a4;
    }
    if (tid < 32) {
        float s = 0.f;
        for (int blk = 0; blk < 64; ++blk) s += partials[blk * 1056 + 1024 + tid];
        mu[tid] = s * (1.f / 16384.f);
    }
    __syncthreads();

    // symmetry fixup: cov[i>=16][j<16] = cov[j][i] (disjoint read/write sets)
    {
        const int fi = 16 + (tid >> 4), fj = tid & 15;
        cov[fi * 32 + fj] = cov[fj * 32 + fi];
    }
    __syncthreads();

    // per-thread BN constants for channel o = tid
    {
        float wo[32];
#pragma unroll
        for (int c8 = 0; c8 < 4; ++c8) {
            const uint4 hv = *(const uint4*)&wh[tid * 40 + c8 * 8];
            const uint4 lv = *(const uint4*)&wl[tid * 40 + c8 * 8];
            const u16* hp = (const u16*)&hv;
            const u16* lp = (const u16*)&lv;
#pragma unroll
            for (int t = 0; t < 8; ++t)
                wo[c8 * 8 + t] = us2f(hp[t]) + us2f(lp[t]);
        }
        float mv = 0.f;
#pragma unroll
        for (int c = 0; c < 32; ++c) mv += wo[c] * mu[c];
        float qacc = 0.f;
        for (int i2 = 0; i2 < 32; ++i2) {
            float t = 0.f;
#pragma unroll
            for (int j2 = 0; j2 < 32; ++j2) t += wo[j2] * cov[i2 * 32 + j2];
            qacc += wo[i2] * t;
        }
        const float var = qacc * (1.f / 16384.f) - mv * mv;
        const float A = gamma[tid] * rsqrtf(var + 1e-5f);
        As[tid] = A;
        Ss[tid] = beta[tid] - A * mv;
    }
    __syncthreads();

    const int w = tid >> 6;
    const int lane = tid & 63;
    const int lm = lane & 15, quad = lane >> 4;

    bf16x8 pb[2];
    pb[0] = *(const bf16x8*)&pL[(0 + lm) * 40 + quad * 8];
    pb[1] = *(const bf16x8*)&pL[(16 + lm) * 40 + quad * 8];

    f32x4 acc[4][2];
#pragma unroll
    for (int mm = 0; mm < 4; ++mm) {
        const int orow = w * 64 + mm * 16 + lm;
        const bf16x8 ah = *(const bf16x8*)&wh[orow * 40 + quad * 8];
        const bf16x8 al = *(const bf16x8*)&wl[orow * 40 + quad * 8];
#pragma unroll
        for (int n = 0; n < 2; ++n) {
            f32x4 t = {0.f, 0.f, 0.f, 0.f};
            t = __builtin_amdgcn_mfma_f32_16x16x32_bf16(ah, pb[n], t, 0, 0, 0);
            acc[mm][n] =
                __builtin_amdgcn_mfma_f32_16x16x32_bf16(al, pb[n], t, 0, 0, 0);
        }
    }

#pragma unroll
    for (int mm = 0; mm < 4; ++mm) {
#pragma unroll
        for (int rg = 0; rg < 4; ++rg) {
            const int o = w * 64 + mm * 16 + quad * 4 + rg;
            const float Ao = As[o], So = Ss[o];
#pragma unroll
            for (int n = 0; n < 2; ++n) {
                const int ga = ((b << 8) + o) * 4096 + p0 + n * 16 + lm;
                out[ga] = x[ga] + Ao * acc[mm][n][rg] + So;
            }
        }
    }
}

extern "C" void kernel_launch(void* const* d_in, const int* in_sizes, int n_in,
                              void* d_out, int out_size, void* d_ws, size_t ws_size,
                              hipStream_t stream)
{
    (void)in_sizes; (void)n_in; (void)out_size; (void)ws_size;
    float* out = (float*)d_out;
    char* ws = (char*)d_ws;

    const float* x      = (const float*)d_in[0];
    const float* vessel = (const float*)d_in[1];
    const float* wk     = (const float*)d_in[2];
    const float* bk     = (const float*)d_in[3];
    const float* wq     = (const float*)d_in[4];
    const float* bq     = (const float*)d_in[5];
    const float* wx     = (const float*)d_in[6];
    const float* bx     = (const float*)d_in[7];
    const float* wf     = (const float*)d_in[8];
    // d_in[9] (bfb) cancels algebraically in training-mode BN — unused.
    const float* gamma  = (const float*)d_in[10];
    const float* beta   = (const float*)d_in[11];

    // Disjoint workspace layout:
    bf16* km  = (bf16*)(ws);
    bf16* qm  = (bf16*)(ws + 1048576);
    bf16* xm  = (bf16*)(ws + 2097152);
    bf16* pre = (bf16*)(ws + 3145728);
    float* partials = (float*)(ws + 4194304);   // 64*1056*4 = 270336 B

    k_proj <<<512, 256, 0, stream>>>(x, vessel, wk, bk, wq, bq, wx, bx,
                                     km, qm, xm, partials);
    k_attn <<<512, 256, 0, stream>>>(km, qm, xm, pre, partials);
    k_out  <<<512, 256, 0, stream>>>(pre, wf, partials, gamma, beta, x, out);
}